// Round 11
// baseline (206.549 us; speedup 1.0000x reference)
//
#include <hip/hip_runtime.h>

#define HID    100
#define INP    4
#define TMAX   256
#define SBR    8      // real sequences per block (cols 8..15 of the MFMA tile unused)
#define ULD    136    // u_lds row stride in halves (272 B, 16B-aligned)
#define NTH    512    // 8 waves -> 2 waves/SIMD per block, 2 blocks/CU -> 4/SIMD
#define NTILES 25

typedef _Float16 half8 __attribute__((ext_vector_type(8)));
typedef float    f32x4 __attribute__((ext_vector_type(4)));

#define L2E  1.442695040888963f
#define L2E2 2.885390081777927f

__device__ __forceinline__ float fexp2(float x) { return __builtin_amdgcn_exp2f(x); }
__device__ __forceinline__ float frcp(float x)  { return __builtin_amdgcn_rcpf(x); }

// ---- counting sort of sequence indices by length, DESCENDING (LPT schedule).
// Output determinism: per-seq results don't depend on block assignment; only
// the (irrelevant) within-bin order is atomic-nondeterministic.
__global__ __launch_bounds__(1024) void sort_by_len(const int* __restrict__ lens,
                                                    int* __restrict__ perm, int N) {
    __shared__ int hist[256];
    __shared__ int base[256];
    __shared__ int cnt[256];
    const int tid = threadIdx.x;
    for (int i = tid; i < 256; i += 1024) { hist[i] = 0; cnt[i] = 0; }
    __syncthreads();
    for (int i = tid; i < N; i += 1024)
        atomicAdd(&hist[256 - lens[i]], 1);
    __syncthreads();
    if (tid == 0) {
        int acc = 0;
        for (int k = 0; k < 256; ++k) { base[k] = acc; acc += hist[k]; }
    }
    __syncthreads();
    for (int i = tid; i < N; i += 1024) {
        int key = 256 - lens[i];
        perm[base[key] + atomicAdd(&cnt[key], 1)] = i;
    }
}

__global__ __launch_bounds__(NTH, 4) void lstm_persist(
    const float* __restrict__ xg,     // [N][T][4]
    const float* __restrict__ w_ih,   // [400][4]
    const float* __restrict__ w_hh,   // [400][100]
    const float* __restrict__ b_ih,   // [400]
    const float* __restrict__ b_hh,   // [400]
    const int*   __restrict__ lens,   // [N]
    const int*   __restrict__ perm,   // [N] sorted seq indices
    float* __restrict__ out)          // [N][100]
{
    __shared__ _Float16 u_lds[2][16 * ULD];   // dbuf [16 rows][136]: h|x|1|pad (rows 8..15 stay 0)
    __shared__ int len_s[SBR];
    __shared__ int sid_s[SBR];
    __shared__ int maxlen_s;

    const int tid  = threadIdx.x;
    const int wave = tid >> 6;
    const int lane = tid & 63;
    const int l15  = lane & 15;    // seq slot (B-col = D-col); real if < 8
    const int l4   = lane >> 4;
    const int g0   = blockIdx.x * SBR;

    if (tid < SBR) {
        int sid = perm[g0 + tid];
        sid_s[tid] = sid;
        len_s[tid] = lens[sid];
    }
    {   // zero both buffers; bias column (k==104) = 1.0
        _Float16* u0 = &u_lds[0][0];
        for (int i = tid; i < 2 * 16 * ULD; i += NTH) {
            int col = i % ULD;
            u0[i] = (col == (HID + INP)) ? (_Float16)1.f : (_Float16)0.f;
        }
    }

    // ---- Weights as A-operand fragments, register-resident, PRESCALED.
    // Wave w owns tiles w, w+8, w+16 (+24 for wave 6): 25 total over 8 waves.
    // Position p = n*16 + l15; ty = p&3 (i,f,g,o); q = p>>2; unit = 25*(q&3)+(q>>2).
    // Row scale folded in: i,f,o -> -log2(e); g -> +2*log2(e).
    half8 afrag[4][4];
    int   tn[4];
    tn[0] = wave; tn[1] = wave + 8; tn[2] = wave + 16;
    tn[3] = (wave == 6) ? 24 : NTILES;
    #pragma unroll
    for (int i = 0; i < 4; ++i) {
        int n = tn[i];
        if (n < NTILES) {
            int p  = n * 16 + l15;
            int ty = p & 3;
            int q  = p >> 2;
            int unit = 25 * (q & 3) + (q >> 2);
            int grow = ty * HID + unit;
            float scale = (ty == 2) ? L2E2 : -L2E;
            #pragma unroll
            for (int c = 0; c < 4; ++c) {
                half8 v;
                #pragma unroll
                for (int j = 0; j < 8; ++j) {
                    int k = c * 32 + l4 * 8 + j;
                    float w;
                    if (k < HID)             w = w_hh[grow * HID + k];
                    else if (k < HID + INP)  w = w_ih[grow * INP + (k - HID)];
                    else if (k == HID + INP) w = b_ih[grow] + b_hh[grow];
                    else                     w = 0.f;
                    v[j] = (_Float16)(scale * w);
                }
                afrag[i][c] = v;
            }
        }
    }

    __syncthreads();
    if (tid == 0) {
        int m = 0;
        for (int s = 0; s < SBR; ++s) m = m > len_s[s] ? m : len_s[s];
        maxlen_s = m;
    }

    // x(0) into buf0; register-prefetch x(1), x(2). Last half of wave 7 does x-duty.
    float xv1 = 0.f, xv2 = 0.f;
    const float* xs = nullptr;
    if (tid >= NTH - 32) {
        int idx = tid - (NTH - 32);
        int s = idx >> 2, ch = idx & 3;
        xs = xg + (size_t)sid_s[s] * TMAX * INP + ch;
        u_lds[0][s * ULD + HID + ch] = (_Float16)xs[0];
        xv1 = xs[INP];
        xv2 = xs[2 * INP];
    }
    float creg[4] = {};
    __syncthreads();

    if (wave & 1) __builtin_amdgcn_s_setprio(1);   // static split (R10)

    const int maxlen = maxlen_s;
    const int mylen  = (l15 < SBR) ? len_s[l15] : 0;
    const int myseq  = (l15 < SBR) ? sid_s[l15] : 0;
    const _Float16* ub0 = &u_lds[0][l15 * ULD + l4 * 8];
    const _Float16* ub1 = &u_lds[1][l15 * ULD + l4 * 8];

    for (int t = 0; t < maxlen; ++t) {
        const _Float16* ub = (t & 1) ? ub1 : ub0;
        _Float16* ubn = (t & 1) ? &u_lds[0][0] : &u_lds[1][0];

        // B-fragments: u for this step (col = l15 = seq slot, k = c*32 + l4*8 + j)
        half8 bfr[4];
        #pragma unroll
        for (int c = 0; c < 4; ++c)
            bfr[c] = *(const half8*)(ub + c * 32);

        // stage x(t+1) into next buffer; issue load of x(t+3)
        if (tid >= NTH - 32) {
            int idx = tid - (NTH - 32);
            int s = idx >> 2, ch = idx & 3;
            ubn[s * ULD + HID + ch] = (_Float16)xv1;
            xv1 = xv2;
            int tt = t + 3;
            xv2 = (tt < TMAX) ? xs[(size_t)tt * INP] : 0.f;
        }

        #pragma unroll
        for (int i = 0; i < 4; ++i) {
            if (tn[i] < NTILES) {
                f32x4 acc = {0.f, 0.f, 0.f, 0.f};
                #pragma unroll
                for (int c = 0; c < 4; ++c)
                    acc = __builtin_amdgcn_mfma_f32_16x16x32_f16(afrag[i][c], bfr[c], acc, 0, 0, 0);
                // lane (l15,l4): seq slot = l15, unit = 25*l4 + tn[i]; r: 0=i 1=f 2=g 3=o
                if (t < mylen) {
                    float e_i = fexp2(acc[0]);                    // exp(-z_i)
                    float e_f = fexp2(acc[1]);                    // exp(-z_f)
                    float e_g = fexp2(acc[2]);                    // exp(+2 z_g)
                    float e_o = fexp2(acc[3]);                    // exp(-z_o)
                    float tg  = 1.f + e_g;
                    float d1  = __builtin_fmaf(e_i, tg, tg);      // (1+e_i)(1+e_g)
                    float r1  = frcp(d1);
                    float ig  = __builtin_fmaf(e_g, r1, -r1);     // i*g
                    float r2  = frcp(1.f + e_f);                  // f
                    float cn  = __builtin_fmaf(r2, creg[i], ig);
                    float e_c = fexp2(fminf(L2E2 * cn, 60.f));    // exp(+2 cn), clamped
                    float t3  = 1.f + e_c;
                    float d3  = __builtin_fmaf(e_o, t3, t3);      // (1+e_o)(1+e_c)
                    float r3  = frcp(d3);
                    float hn  = __builtin_fmaf(e_c, r3, -r3);     // o*tanh(cn)
                    creg[i] = cn;
                    int unit = 25 * l4 + tn[i];
                    ubn[l15 * ULD + unit] = (_Float16)hn;
                    if (t == mylen - 1)
                        out[(size_t)myseq * HID + unit] = hn;
                }
            }
        }
        // lgkm-only drain (R9): LDS h/x writes visible; global x-load stays in flight
        asm volatile("s_waitcnt lgkmcnt(0)" ::: "memory");
        __builtin_amdgcn_s_barrier();
    }
}

extern "C" void kernel_launch(void* const* d_in, const int* in_sizes, int n_in,
                              void* d_out, int out_size, void* d_ws, size_t ws_size,
                              hipStream_t stream) {
    const float* xg   = (const float*)d_in[0];
    const float* w_ih = (const float*)d_in[1];
    const float* w_hh = (const float*)d_in[2];
    const float* b_ih = (const float*)d_in[3];
    const float* b_hh = (const float*)d_in[4];
    const int*   lens = (const int*)d_in[5];
    float* out = (float*)d_out;
    const int N = in_sizes[5];           // 4096
    int* perm = (int*)d_ws;              // N ints of scratch
    sort_by_len<<<1, 1024, 0, stream>>>(lens, perm, N);
    lstm_persist<<<dim3(N / SBR), NTH, 0, stream>>>(xg, w_ih, w_hh, b_ih, b_hh,
                                                    lens, perm, out);
}

// Round 12
// 178.409 us; speedup vs baseline: 1.1577x; 1.1577x over previous
//
#include <hip/hip_runtime.h>

#define HID    100
#define INP    4
#define TMAX   256
#define SB     16     // sequences per block = full MFMA M/N
#define ULD    136    // u_lds row stride in halves (272 B, 16B-aligned)
#define NTH    1024   // 16 waves -> 4 waves/SIMD
#define NTILES 25

typedef _Float16 half8  __attribute__((ext_vector_type(8)));
typedef _Float16 half2v __attribute__((ext_vector_type(2)));
typedef float    f32x4  __attribute__((ext_vector_type(4)));

#define L2E  1.442695040888963f
#define L2E2 2.885390081777927f

__device__ __forceinline__ float fexp2(float x) { return __builtin_amdgcn_exp2f(x); }
__device__ __forceinline__ float frcp(float x)  { return __builtin_amdgcn_rcpf(x); }

// Storage position (= PyTorch unit index, bijective on 0..99) for tile n,
// unit-group g (0..3). Pairs: tiles {w, w+16} (w<9) -> adjacent (even, odd)
// positions so one lane writes both h values with a single ds_write_b32.
__device__ __forceinline__ int pos_for(int n, int g) {
    int base = 25 * g;
    int e = base + (base & 1);          // first even position >= base
    if (n < 9)   return e + 2 * n;          // paired low  (even)
    if (n >= 16) return e + 2 * (n - 16) + 1; // paired high (odd)
    // singles: tiles 9..15
    if (base & 1) return (n == 9) ? base : base + 19 + (n - 10);
    return base + 18 + (n - 9);
}

__global__ __launch_bounds__(NTH) void lstm_persist(
    const float* __restrict__ xg,     // [N][T][4]
    const float* __restrict__ w_ih,   // [400][4]
    const float* __restrict__ w_hh,   // [400][100]
    const float* __restrict__ b_ih,   // [400]
    const float* __restrict__ b_hh,   // [400]
    const int*   __restrict__ lens,   // [N]
    float* __restrict__ out)          // [N][100]
{
    __shared__ _Float16 u_lds[2][SB * ULD];   // dbuf [seq][136]: h[0..99] | x[100..103] | 1 | 0-pad
    __shared__ int len_s[SB];
    __shared__ int maxlen_s;

    const int tid  = threadIdx.x;
    const int wave = tid >> 6;
    const int lane = tid & 63;
    const int l15  = lane & 15;    // seq (B-col = D-col)
    const int l4   = lane >> 4;
    const int seq0 = blockIdx.x * SB;

    if (tid < SB) len_s[tid] = lens[seq0 + tid];
    {   // zero both buffers; bias column (k==104) = 1.0
        _Float16* u0 = &u_lds[0][0];
        for (int i = tid; i < 2 * SB * ULD; i += NTH) {
            int col = i % ULD;
            u0[i] = (col == (HID + INP)) ? (_Float16)1.f : (_Float16)0.f;
        }
    }

    // ---- Weights as A-operand fragments, register-resident, PRESCALED.
    // Wave w owns tile w (and w+16 if < 25).
    // A-row l15 of tile n = position p = n*16 + l15: ty = l15&3 (i,f,g,o),
    // unit-group = l15>>2, stored/logical unit = pos_for(n, l15>>2).
    // Row scale folded in: i,f,o -> -log2(e); g -> +2*log2(e).
    half8 afrag[2][4];
    int   tn[2];
    tn[0] = wave;
    tn[1] = (wave + 16 < NTILES) ? wave + 16 : NTILES;
    #pragma unroll
    for (int i = 0; i < 2; ++i) {
        int n = tn[i];
        if (n < NTILES) {
            int ty   = l15 & 3;
            int unit = pos_for(n, l15 >> 2);
            int grow = ty * HID + unit;
            float scale = (ty == 2) ? L2E2 : -L2E;
            #pragma unroll
            for (int c = 0; c < 4; ++c) {
                half8 v;
                #pragma unroll
                for (int j = 0; j < 8; ++j) {
                    int k = c * 32 + l4 * 8 + j;
                    float w;
                    if (k < HID)             w = w_hh[grow * HID + k];
                    else if (k < HID + INP)  w = w_ih[grow * INP + (k - HID)];
                    else if (k == HID + INP) w = b_ih[grow] + b_hh[grow];
                    else                     w = 0.f;
                    v[j] = (_Float16)(scale * w);
                }
                afrag[i][c] = v;
            }
        }
    }

    __syncthreads();
    if (tid == 0) {
        int m = 0;
        for (int s = 0; s < SB; ++s) m = m > len_s[s] ? m : len_s[s];
        maxlen_s = m;
    }

    // x(0) into buf0; register-prefetch x(1), x(2). Wave 15 does x-duty.
    float xv1 = 0.f, xv2 = 0.f;
    const float* xs = nullptr;
    if (tid >= NTH - 64) {
        int idx = tid - (NTH - 64);
        int s = idx >> 2, ch = idx & 3;
        xs = xg + (size_t)(seq0 + s) * TMAX * INP + ch;
        u_lds[0][s * ULD + HID + ch] = (_Float16)xs[0];
        xv1 = xs[INP];
        xv2 = xs[2 * INP];
    }
    float creg[2] = {};
    __syncthreads();

    if (wave & 1) __builtin_amdgcn_s_setprio(1);   // static split (R10)

    // D-side storage positions for this lane's tiles (update phase uses l4)
    const bool has2 = (wave < 9);
    const int  pos0 = pos_for(tn[0], l4);               // even when has2
    const int  pos1 = has2 ? pos_for(tn[1], l4) : 0;    // = pos0 + 1

    const int maxlen = maxlen_s;
    const int mylen  = len_s[l15];
    const _Float16* ub0 = &u_lds[0][l15 * ULD + l4 * 8];
    const _Float16* ub1 = &u_lds[1][l15 * ULD + l4 * 8];

    for (int t = 0; t < maxlen; ++t) {
        const _Float16* ub = (t & 1) ? ub1 : ub0;
        _Float16* ubn = (t & 1) ? &u_lds[0][0] : &u_lds[1][0];

        // B-fragments: u for this step (col = l15 = seq, k = c*32 + l4*8 + j)
        half8 bfr[4];
        #pragma unroll
        for (int c = 0; c < 4; ++c)
            bfr[c] = *(const half8*)(ub + c * 32);

        // stage x(t+1) into next buffer; issue load of x(t+3)
        if (tid >= NTH - 64) {
            int idx = tid - (NTH - 64);
            int s = idx >> 2, ch = idx & 3;
            ubn[s * ULD + HID + ch] = (_Float16)xv1;
            xv1 = xv2;
            int tt = t + 3;
            xv2 = (tt < TMAX) ? xs[(size_t)tt * INP] : 0.f;
        }

        f32x4 acc0 = {0.f, 0.f, 0.f, 0.f};
        #pragma unroll
        for (int c = 0; c < 4; ++c)
            acc0 = __builtin_amdgcn_mfma_f32_16x16x32_f16(afrag[0][c], bfr[c], acc0, 0, 0, 0);
        f32x4 acc1 = {0.f, 0.f, 0.f, 0.f};
        if (has2) {
            #pragma unroll
            for (int c = 0; c < 4; ++c)
                acc1 = __builtin_amdgcn_mfma_f32_16x16x32_f16(afrag[1][c], bfr[c], acc1, 0, 0, 0);
        }

        // lane (l15,l4): seq = l15, units pos0 (and pos1); acc r: 0=i 1=f 2=g 3=o
        // prescaled: i,f,o hold -z*log2e ; g holds +2*z*log2e
        if (t < mylen) {
            // tile 0 update (7 trans: 5 exp + 2 rcp, merged f-reciprocal)
            float e_i = fexp2(acc0[0]);
            float e_f = fexp2(acc0[1]);
            float e_g = fexp2(acc0[2]);
            float e_o = fexp2(acc0[3]);
            float tg  = 1.f + e_g;
            float df  = 1.f + e_f;
            float d1  = __builtin_fmaf(e_i, tg, tg);      // (1+e_i)(1+e_g)
            float r12 = frcp(d1 * df);
            float r1  = df * r12;                          // 1/d1
            float fm  = d1 * r12;                          // f
            float ig  = __builtin_fmaf(e_g, r1, -r1);      // i*g
            float cn  = __builtin_fmaf(fm, creg[0], ig);
            float e_c = fexp2(fminf(L2E2 * cn, 60.f));
            float t3  = 1.f + e_c;
            float d3  = __builtin_fmaf(e_o, t3, t3);       // (1+e_o)(1+e_c)
            float r3  = frcp(d3);
            float hn0 = __builtin_fmaf(e_c, r3, -r3);      // o*tanh(cn)
            creg[0] = cn;

            float hn1 = 0.f;
            if (has2) {
                float f_i = fexp2(acc1[0]);
                float f_f = fexp2(acc1[1]);
                float f_g = fexp2(acc1[2]);
                float f_o = fexp2(acc1[3]);
                float ug  = 1.f + f_g;
                float uf  = 1.f + f_f;
                float u1  = __builtin_fmaf(f_i, ug, ug);
                float s12 = frcp(u1 * uf);
                float s1  = uf * s12;
                float um  = u1 * s12;
                float jg  = __builtin_fmaf(f_g, s1, -s1);
                float dn  = __builtin_fmaf(um, creg[1], jg);
                float f_c = fexp2(fminf(L2E2 * dn, 60.f));
                float u3  = 1.f + f_c;
                float w3  = __builtin_fmaf(f_o, u3, u3);
                float s3  = frcp(w3);
                hn1 = __builtin_fmaf(f_c, s3, -s3);
                creg[1] = dn;
            }

            if (has2) {
                half2v pk = {(_Float16)hn0, (_Float16)hn1};
                *(half2v*)(ubn + l15 * ULD + pos0) = pk;   // one b32 write
            } else {
                ubn[l15 * ULD + pos0] = (_Float16)hn0;
            }
            if (t == mylen - 1) {
                out[(size_t)(seq0 + l15) * HID + pos0] = hn0;
                if (has2) out[(size_t)(seq0 + l15) * HID + pos1] = hn1;
            }
        }
        // lgkm-only drain (R9): LDS writes visible; global x-load stays in flight
        asm volatile("s_waitcnt lgkmcnt(0)" ::: "memory");
        __builtin_amdgcn_s_barrier();
    }
}

extern "C" void kernel_launch(void* const* d_in, const int* in_sizes, int n_in,
                              void* d_out, int out_size, void* d_ws, size_t ws_size,
                              hipStream_t stream) {
    const float* xg   = (const float*)d_in[0];
    const float* w_ih = (const float*)d_in[1];
    const float* w_hh = (const float*)d_in[2];
    const float* b_ih = (const float*)d_in[3];
    const float* b_hh = (const float*)d_in[4];
    const int*   lens = (const int*)d_in[5];
    float* out = (float*)d_out;
    const int N = in_sizes[5];           // 4096
    lstm_persist<<<dim3(N / SB), NTH, 0, stream>>>(xg, w_ih, w_hh, b_ih, b_hh, lens, out);
}

// Round 13
// 175.392 us; speedup vs baseline: 1.1776x; 1.0172x over previous
//
#include <hip/hip_runtime.h>

#define HID    100
#define INP    4
#define TMAX   256
#define SB     16     // sequences per block = full MFMA M/N
#define ULD    136    // u_lds row stride in halves (272 B, 16B-aligned)
#define NTH    1024   // 16 waves -> 4 waves/SIMD
#define NTILES 25

typedef _Float16 half8 __attribute__((ext_vector_type(8)));
typedef float    f32x4 __attribute__((ext_vector_type(4)));

#define L2E  1.442695040888963f
#define L2E2 2.885390081777927f

__device__ __forceinline__ float fexp2(float x) { return __builtin_amdgcn_exp2f(x); }
__device__ __forceinline__ float frcp(float x)  { return __builtin_amdgcn_rcpf(x); }

__global__ __launch_bounds__(NTH) void lstm_persist(
    const float* __restrict__ xg,     // [N][T][4]
    const float* __restrict__ w_ih,   // [400][4]
    const float* __restrict__ w_hh,   // [400][100]
    const float* __restrict__ b_ih,   // [400]
    const float* __restrict__ b_hh,   // [400]
    const int*   __restrict__ lens,   // [N]
    float* __restrict__ out)          // [N][100]
{
    __shared__ _Float16 u_lds[2][SB * ULD];   // dbuf [seq][136]: h[0..99] | x[100..103] | 1 | 0-pad
    __shared__ int len_s[SB];
    __shared__ int maxlen_s;

    const int tid  = threadIdx.x;
    const int wave = tid >> 6;
    const int lane = tid & 63;
    const int l15  = lane & 15;    // seq (B-col = D-col)
    const int l4   = lane >> 4;
    const int seq0 = blockIdx.x * SB;

    if (tid < SB) len_s[tid] = lens[seq0 + tid];
    {   // zero both buffers; bias column (k==104) = 1.0
        _Float16* u0 = &u_lds[0][0];
        for (int i = tid; i < 2 * SB * ULD; i += NTH) {
            int col = i % ULD;
            u0[i] = (col == (HID + INP)) ? (_Float16)1.f : (_Float16)0.f;
        }
    }

    // ---- Weights as A-operand fragments, register-resident, PRESCALED.
    // Wave w owns tile w (and w+16 if < 25).
    // Position p = n*16 + l15: ty = l15&3 (i,f,g,o), unit = 25*(l15>>2) + n.
    // Row scale folded in: i,f,o -> -log2(e); g -> +2*log2(e).
    half8 afrag[2][4];
    int   tn[2];
    tn[0] = wave;
    tn[1] = (wave + 16 < NTILES) ? wave + 16 : NTILES;
    #pragma unroll
    for (int i = 0; i < 2; ++i) {
        int n = tn[i];
        if (n < NTILES) {
            int ty   = l15 & 3;
            int unit = 25 * (l15 >> 2) + n;
            int grow = ty * HID + unit;
            float scale = (ty == 2) ? L2E2 : -L2E;
            #pragma unroll
            for (int c = 0; c < 4; ++c) {
                half8 v;
                #pragma unroll
                for (int j = 0; j < 8; ++j) {
                    int k = c * 32 + l4 * 8 + j;
                    float w;
                    if (k < HID)             w = w_hh[grow * HID + k];
                    else if (k < HID + INP)  w = w_ih[grow * INP + (k - HID)];
                    else if (k == HID + INP) w = b_ih[grow] + b_hh[grow];
                    else                     w = 0.f;
                    v[j] = (_Float16)(scale * w);
                }
                afrag[i][c] = v;
            }
        }
    }

    __syncthreads();
    if (tid == 0) {
        int m = 0;
        for (int s = 0; s < SB; ++s) m = m > len_s[s] ? m : len_s[s];
        maxlen_s = m;
    }

    // x(0) into buf0; register-prefetch x(1), x(2). Wave 15 does x-duty.
    float xv1 = 0.f, xv2 = 0.f;
    const float* xs = nullptr;
    if (tid >= NTH - 64) {
        int idx = tid - (NTH - 64);
        int s = idx >> 2, ch = idx & 3;
        xs = xg + (size_t)(seq0 + s) * TMAX * INP + ch;
        u_lds[0][s * ULD + HID + ch] = (_Float16)xs[0];
        xv1 = xs[INP];
        xv2 = xs[2 * INP];
    }
    float creg[2] = {};
    __syncthreads();

    if (wave & 1) __builtin_amdgcn_s_setprio(1);   // static split (R10)

    const bool has2  = (tn[1] < NTILES);
    const int  maxlen = maxlen_s;
    const int  mylen  = len_s[l15];
    const _Float16* ubr0 = &u_lds[0][l15 * ULD + l4 * 8];
    const _Float16* ubr1 = &u_lds[1][l15 * ULD + l4 * 8];
    _Float16* ubw0 = &u_lds[0][0];
    _Float16* ubw1 = &u_lds[1][0];

    // one LSTM step: read ubr, write ubw (compile-time buffer selection)
    auto step = [&](const _Float16* ubr, _Float16* ubw, int t) {
        // B-fragments: u for this step (col = l15 = seq, k = c*32 + l4*8 + j)
        half8 bfr[4];
        #pragma unroll
        for (int c = 0; c < 4; ++c)
            bfr[c] = *(const half8*)(ubr + c * 32);

        f32x4 acc0 = {0.f, 0.f, 0.f, 0.f};
        #pragma unroll
        for (int c = 0; c < 4; ++c)
            acc0 = __builtin_amdgcn_mfma_f32_16x16x32_f16(afrag[0][c], bfr[c], acc0, 0, 0, 0);
        f32x4 acc1 = {0.f, 0.f, 0.f, 0.f};
        if (has2) {
            #pragma unroll
            for (int c = 0; c < 4; ++c)
                acc1 = __builtin_amdgcn_mfma_f32_16x16x32_f16(afrag[1][c], bfr[c], acc1, 0, 0, 0);
        }

        // stage x(t+1) into the buffer being written; issue load of x(t+3)
        if (tid >= NTH - 64) {
            int idx = tid - (NTH - 64);
            int s = idx >> 2, ch = idx & 3;
            ubw[s * ULD + HID + ch] = (_Float16)xv1;
            xv1 = xv2;
            int tt = t + 3;
            xv2 = (tt < TMAX) ? xs[(size_t)tt * INP] : 0.f;
        }

        // lane (l15,l4): seq = l15, unit = 25*l4 + tn[i]; acc r: 0=i 1=f 2=g 3=o
        // prescaled: i,f,o hold -z*log2e ; g holds +2*z*log2e
        // single-rcp c-update: cn = (c*A + P) / (A*df),
        //   A = (1+e_i)(1+e_g), P = (e_g-1)(1+e_f), df = 1+e_f
        if (t < mylen) {
            float e_i = fexp2(acc0[0]);
            float e_f = fexp2(acc0[1]);
            float e_g = fexp2(acc0[2]);
            float e_o = fexp2(acc0[3]);
            float tg  = 1.f + e_g;
            float df  = 1.f + e_f;
            float A   = __builtin_fmaf(e_i, tg, tg);
            float P   = __builtin_fmaf(e_g, df, -df);
            float num = __builtin_fmaf(creg[0], A, P);
            float cn  = num * frcp(A * df);
            float e_c = fexp2(fminf(L2E2 * cn, 60.f));
            float t3  = 1.f + e_c;
            float d3  = __builtin_fmaf(e_o, t3, t3);      // (1+e_o)(1+e_c)
            float r3  = frcp(d3);
            float hn0 = __builtin_fmaf(e_c, r3, -r3);     // o*tanh(cn)
            creg[0] = cn;
            int unit0 = 25 * l4 + tn[0];
            ubw[l15 * ULD + unit0] = (_Float16)hn0;

            if (has2) {
                float f_i = fexp2(acc1[0]);
                float f_f = fexp2(acc1[1]);
                float f_g = fexp2(acc1[2]);
                float f_o = fexp2(acc1[3]);
                float ug  = 1.f + f_g;
                float uf  = 1.f + f_f;
                float B   = __builtin_fmaf(f_i, ug, ug);
                float Q   = __builtin_fmaf(f_g, uf, -uf);
                float nm2 = __builtin_fmaf(creg[1], B, Q);
                float dn  = nm2 * frcp(B * uf);
                float f_c = fexp2(fminf(L2E2 * dn, 60.f));
                float u3  = 1.f + f_c;
                float w3  = __builtin_fmaf(f_o, u3, u3);
                float s3  = frcp(w3);
                float hn1 = __builtin_fmaf(f_c, s3, -s3);
                creg[1] = dn;
                int unit1 = 25 * l4 + tn[1];
                ubw[l15 * ULD + unit1] = (_Float16)hn1;
                if (t == mylen - 1) {
                    out[(size_t)(seq0 + l15) * HID + unit0] = hn0;
                    out[(size_t)(seq0 + l15) * HID + unit1] = hn1;
                }
            } else if (t == mylen - 1) {
                out[(size_t)(seq0 + l15) * HID + unit0] = hn0;
            }
        }
        // lgkm-only drain (R9): LDS writes visible; global x-load stays in flight
        asm volatile("s_waitcnt lgkmcnt(0)" ::: "memory");
        __builtin_amdgcn_s_barrier();
    };

    int t = 0;
    while (true) {
        step(ubr0, ubw1, t);            // even step: read buf0, write buf1
        if (++t >= maxlen) break;
        step(ubr1, ubw0, t);            // odd step: read buf1, write buf0
        if (++t >= maxlen) break;
    }
}

extern "C" void kernel_launch(void* const* d_in, const int* in_sizes, int n_in,
                              void* d_out, int out_size, void* d_ws, size_t ws_size,
                              hipStream_t stream) {
    const float* xg   = (const float*)d_in[0];
    const float* w_ih = (const float*)d_in[1];
    const float* w_hh = (const float*)d_in[2];
    const float* b_ih = (const float*)d_in[3];
    const float* b_hh = (const float*)d_in[4];
    const int*   lens = (const int*)d_in[5];
    float* out = (float*)d_out;
    const int N = in_sizes[5];           // 4096
    lstm_persist<<<dim3(N / SB), NTH, 0, stream>>>(xg, w_ih, w_hh, b_ih, b_hh, lens, out);
}

// Round 14
// 162.066 us; speedup vs baseline: 1.2745x; 1.0822x over previous
//
#include <hip/hip_runtime.h>

#define HID    100
#define INP    4
#define TMAX   256
#define SB     16     // sequences per block = full MFMA M/N
#define ULD    136    // u_lds row stride in halves (272 B, 16B-aligned)
#define NTH    1024   // 16 waves -> 4 waves/SIMD
#define NTILES 25

typedef _Float16 half8 __attribute__((ext_vector_type(8)));
typedef float    f32x4 __attribute__((ext_vector_type(4)));

#define L2E  1.442695040888963f
#define L2E2 2.885390081777927f

__device__ __forceinline__ float fexp2(float x) { return __builtin_amdgcn_exp2f(x); }
__device__ __forceinline__ float frcp(float x)  { return __builtin_amdgcn_rcpf(x); }

__global__ __launch_bounds__(NTH) void lstm_persist(
    const float* __restrict__ xg,     // [N][T][4]
    const float* __restrict__ w_ih,   // [400][4]
    const float* __restrict__ w_hh,   // [400][100]
    const float* __restrict__ b_ih,   // [400]
    const float* __restrict__ b_hh,   // [400]
    const int*   __restrict__ lens,   // [N]
    float* __restrict__ out)          // [N][100]
{
    __shared__ _Float16 u_lds[2][SB * ULD];   // dbuf [seq][136]: h[0..99] | x[100..103] | 1 | 0-pad
    __shared__ int len_s[SB];
    __shared__ int maxlen_s;

    const int tid  = threadIdx.x;
    const int wave = tid >> 6;
    const int lane = tid & 63;
    const int l15  = lane & 15;    // seq (B-col = D-col)
    const int l4   = lane >> 4;
    const int seq0 = blockIdx.x * SB;

    if (tid < SB) len_s[tid] = lens[seq0 + tid];
    {   // zero both buffers; bias column (k==104) = 1.0
        _Float16* u0 = &u_lds[0][0];
        for (int i = tid; i < 2 * SB * ULD; i += NTH) {
            int col = i % ULD;
            u0[i] = (col == (HID + INP)) ? (_Float16)1.f : (_Float16)0.f;
        }
    }

    // ---- Weights as A-operand fragments, register-resident, PRESCALED.
    // Wave w owns tile w (and w+16 if < 25).
    // Position p = n*16 + l15: ty = l15&3 (i,f,g,o), unit = 25*(l15>>2) + n.
    // Row scale folded in: i,f,o -> -log2(e); g -> +2*log2(e).
    half8 afrag[2][4];
    int   tn[2];
    tn[0] = wave;
    tn[1] = (wave + 16 < NTILES) ? wave + 16 : NTILES;
    #pragma unroll
    for (int i = 0; i < 2; ++i) {
        int n = tn[i];
        if (n < NTILES) {
            int ty   = l15 & 3;
            int unit = 25 * (l15 >> 2) + n;
            int grow = ty * HID + unit;
            float scale = (ty == 2) ? L2E2 : -L2E;
            #pragma unroll
            for (int c = 0; c < 4; ++c) {
                half8 v;
                #pragma unroll
                for (int j = 0; j < 8; ++j) {
                    int k = c * 32 + l4 * 8 + j;
                    float w;
                    if (k < HID)             w = w_hh[grow * HID + k];
                    else if (k < HID + INP)  w = w_ih[grow * INP + (k - HID)];
                    else if (k == HID + INP) w = b_ih[grow] + b_hh[grow];
                    else                     w = 0.f;
                    v[j] = (_Float16)(scale * w);
                }
                afrag[i][c] = v;
            }
        }
    }

    __syncthreads();
    if (tid == 0) {
        int m = 0;
        for (int s = 0; s < SB; ++s) m = m > len_s[s] ? m : len_s[s];
        maxlen_s = m;
    }

    // x(0) into buf0; register-prefetch x(1), x(2). Wave 15 does x-duty.
    float xv1 = 0.f, xv2 = 0.f;
    const float* xs = nullptr;
    if (tid >= NTH - 64) {
        int idx = tid - (NTH - 64);
        int s = idx >> 2, ch = idx & 3;
        xs = xg + (size_t)(seq0 + s) * TMAX * INP + ch;
        u_lds[0][s * ULD + HID + ch] = (_Float16)xs[0];
        xv1 = xs[INP];
        xv2 = xs[2 * INP];
    }
    float creg[2] = {};
    __syncthreads();

    if (wave & 1) __builtin_amdgcn_s_setprio(1);   // static split (R10)

    const int maxlen = maxlen_s;
    const int mylen  = len_s[l15];
    const _Float16* ub0 = &u_lds[0][l15 * ULD + l4 * 8];
    const _Float16* ub1 = &u_lds[1][l15 * ULD + l4 * 8];

    for (int t = 0; t < maxlen; ++t) {
        const _Float16* ub = (t & 1) ? ub1 : ub0;
        _Float16* ubn = (t & 1) ? &u_lds[0][0] : &u_lds[1][0];

        // B-fragments: u for this step (col = l15 = seq, k = c*32 + l4*8 + j)
        half8 bfr[4];
        #pragma unroll
        for (int c = 0; c < 4; ++c)
            bfr[c] = *(const half8*)(ub + c * 32);

        // stage x(t+1) into next buffer; issue load of x(t+3)
        if (tid >= NTH - 64) {
            int idx = tid - (NTH - 64);
            int s = idx >> 2, ch = idx & 3;
            ubn[s * ULD + HID + ch] = (_Float16)xv1;
            xv1 = xv2;
            int tt = t + 3;
            xv2 = (tt < TMAX) ? xs[(size_t)tt * INP] : 0.f;
        }

        #pragma unroll
        for (int i = 0; i < 2; ++i) {
            if (tn[i] < NTILES) {
                f32x4 acc = {0.f, 0.f, 0.f, 0.f};
                #pragma unroll
                for (int c = 0; c < 4; ++c)
                    acc = __builtin_amdgcn_mfma_f32_16x16x32_f16(afrag[i][c], bfr[c], acc, 0, 0, 0);
                // acc[r] = prescaled preactivation; r: 0=i 1=f 2=g 3=o
                // lane (l15,l4): seq = l15, unit = 25*l4 + tn[i]
                // single-rcp c-update: cn = (c*A + P) * rcp(A*df)
                //   A = (1+e_i)(1+e_g), P = (e_g-1)(1+e_f), df = 1+e_f
                if (t < mylen) {
                    float e_i = fexp2(acc[0]);                    // exp(-z_i)
                    float e_f = fexp2(acc[1]);                    // exp(-z_f)
                    float e_g = fexp2(acc[2]);                    // exp(+2 z_g)
                    float e_o = fexp2(acc[3]);                    // exp(-z_o)
                    float tg  = 1.f + e_g;
                    float df  = 1.f + e_f;
                    float A   = __builtin_fmaf(e_i, tg, tg);      // (1+e_i)(1+e_g)
                    float P   = __builtin_fmaf(e_g, df, -df);     // (e_g-1)(1+e_f)
                    float num = __builtin_fmaf(creg[i], A, P);
                    float cn  = num * frcp(A * df);
                    float e_c = fexp2(fminf(L2E2 * cn, 60.f));    // exp(+2 cn), clamped
                    float t3  = 1.f + e_c;
                    float d3  = __builtin_fmaf(e_o, t3, t3);      // (1+e_o)(1+e_c)
                    float r3  = frcp(d3);
                    float hn  = __builtin_fmaf(e_c, r3, -r3);     // o*tanh(cn)
                    creg[i] = cn;
                    int unit = 25 * l4 + tn[i];
                    ubn[l15 * ULD + unit] = (_Float16)hn;
                    if (t == mylen - 1)
                        out[(size_t)(seq0 + l15) * HID + unit] = hn;
                }
            }
        }
        // lgkm-only drain (R9): LDS writes visible; global x-load stays in flight
        asm volatile("s_waitcnt lgkmcnt(0)" ::: "memory");
        __builtin_amdgcn_s_barrier();
    }
}

extern "C" void kernel_launch(void* const* d_in, const int* in_sizes, int n_in,
                              void* d_out, int out_size, void* d_ws, size_t ws_size,
                              hipStream_t stream) {
    const float* xg   = (const float*)d_in[0];
    const float* w_ih = (const float*)d_in[1];
    const float* w_hh = (const float*)d_in[2];
    const float* b_ih = (const float*)d_in[3];
    const float* b_hh = (const float*)d_in[4];
    const int*   lens = (const int*)d_in[5];
    float* out = (float*)d_out;
    const int N = in_sizes[5];           // 4096
    lstm_persist<<<dim3(N / SB), NTH, 0, stream>>>(xg, w_ih, w_hh, b_ih, b_hh, lens, out);
}